// Round 2
// baseline (1210.291 us; speedup 1.0000x reference)
//
#include <hip/hip_runtime.h>

#define NN 100000
#define FIN 1433
#define KSTEPS 45   // ceil(1433/32)

typedef __attribute__((ext_vector_type(8))) short s16x8;
typedef __attribute__((ext_vector_type(4))) float f32x4;

__device__ __forceinline__ short f2bf(float f){
  unsigned u = __float_as_uint(f);
  unsigned r = (u + 0x7fffu + ((u >> 16) & 1u)) >> 16;
  return (short)r;
}

__device__ __forceinline__ f32x4 mfma16(s16x8 a, s16x8 b, f32x4 c){
  return __builtin_amdgcn_mfma_f32_16x16x32_bf16(a, b, c, 0, 0, 0);
}

// ---------------- CSR build ----------------
__global__ void hist_k(const int* __restrict__ dsts, int* __restrict__ counts, int E){
  int i = blockIdx.x * 256 + threadIdx.x;
  if (i < E) atomicAdd(&counts[dsts[i]], 1);
}

__global__ void scan_k(const int* __restrict__ counts, int* __restrict__ rowp,
                       int* __restrict__ cursor, int n, int E){
  __shared__ int sums[1024];
  int t = threadIdx.x;
  int chunk = (n + 1023) / 1024;
  int beg = t * chunk;
  int end = min(beg + chunk, n);
  int s = 0;
  for (int i = beg; i < end; i++) s += counts[i];
  sums[t] = s;
  __syncthreads();
  for (int off = 1; off < 1024; off <<= 1){
    int v = (t >= off) ? sums[t - off] : 0;
    __syncthreads();
    sums[t] += v;
    __syncthreads();
  }
  int run = (t == 0) ? 0 : sums[t - 1];
  for (int i = beg; i < end; i++){
    int c = counts[i];
    rowp[i] = run;
    cursor[i] = run;
    run += c;
  }
  if (t == 1023) rowp[n] = sums[1023];
}

__global__ void scatter_k(const int* __restrict__ srcs, const int* __restrict__ dsts,
                          int* __restrict__ cursor, int* __restrict__ colv, int E){
  int i = blockIdx.x * 256 + threadIdx.x;
  if (i < E){
    int d = dsts[i];
    int p = atomicAdd(&cursor[d], 1);
    colv[p] = srcs[i];
  }
}

// ---------------- W1 fragment prepack ----------------
// pack[((ks*4+nf)*64 + lane)*8 + j] = bf16( W1[(ks*32 + (lane>>4)*8 + j)][nf*16 + (lane&15)] )
__global__ void w1pack_k(const float* __restrict__ W1, short* __restrict__ pack){
  int ks = blockIdx.x >> 2, nf = blockIdx.x & 3, l = threadIdx.x;
  int col = nf * 16 + (l & 15);
  s16x8 v;
  #pragma unroll
  for (int j = 0; j < 8; j++){
    int k = ks * 32 + ((l >> 4) * 8) + j;
    float f = (k < FIN) ? W1[k * 64 + col] : 0.0f;
    v[j] = f2bf(f);
  }
  *(s16x8*)&pack[((size_t)(ks * 4 + nf) * 64 + l) * 8] = v;
}

// ---------------- GEMM1: h1 = x @ W1  [N,64] ----------------
__global__ __launch_bounds__(256) void gemm1_k(const float* __restrict__ x,
                                               const short* __restrict__ w1p,
                                               float* __restrict__ h1, int n){
  __shared__ float As[128 * 32];   // f32, 16B-granule XOR swizzled
  int tid = threadIdx.x;
  int wid = tid >> 6, lane = tid & 63;
  int row0 = blockIdx.x * 128;
  f32x4 acc[2][4] = {};

  for (int ks = 0; ks < KSTEPS; ks++){
    int k0 = ks * 32;
    // stage A: 128 rows x 32 cols f32 (4096 elems, 16/thread), swizzled
    #pragma unroll
    for (int i = 0; i < 16; i++){
      int e = tid + 256 * i;
      int r = e >> 5, c = e & 31;
      int gr = row0 + r, gc = k0 + c;
      float v = 0.0f;
      if (gr < n && gc < FIN) v = x[(size_t)gr * FIN + gc];
      int gs = (c >> 2) ^ (r & 7);
      As[r * 32 + gs * 4 + (c & 3)] = v;
    }
    __syncthreads();

    // B frags from prepacked global (L2-resident)
    s16x8 b[4];
    #pragma unroll
    for (int nf = 0; nf < 4; nf++)
      b[nf] = *(const s16x8*)&w1p[((size_t)(ks * 4 + nf) * 64 + lane) * 8];

    // A frags from LDS (f32 -> bf16)
    s16x8 a[2];
    #pragma unroll
    for (int mf = 0; mf < 2; mf++){
      int r = wid * 32 + mf * 16 + (lane & 15);
      int gb = (lane >> 4) * 2;
      f32x4 lo = *(const f32x4*)&As[r * 32 + ((gb    ) ^ (r & 7)) * 4];
      f32x4 hi = *(const f32x4*)&As[r * 32 + ((gb + 1) ^ (r & 7)) * 4];
      #pragma unroll
      for (int j = 0; j < 4; j++){ a[mf][j] = f2bf(lo[j]); a[mf][j + 4] = f2bf(hi[j]); }
    }

    #pragma unroll
    for (int mf = 0; mf < 2; mf++)
      #pragma unroll
      for (int nf = 0; nf < 4; nf++)
        acc[mf][nf] = mfma16(a[mf], b[nf], acc[mf][nf]);
    __syncthreads();
  }

  // epilogue: D lane l reg r -> (m=(l>>4)*4+r, ncol=l&15)
  #pragma unroll
  for (int mf = 0; mf < 2; mf++){
    #pragma unroll
    for (int r4 = 0; r4 < 4; r4++){
      int m = row0 + wid * 32 + mf * 16 + (lane >> 4) * 4 + r4;
      if (m < n){
        #pragma unroll
        for (int nf = 0; nf < 4; nf++)
          h1[(size_t)m * 64 + nf * 16 + (lane & 15)] = acc[mf][nf][r4];
      }
    }
  }
}

// ---------------- per-node attention logits, layer 1 ----------------
__global__ void alphas1_k(const float* __restrict__ h1, const float* __restrict__ a1s,
                          const float* __restrict__ a1d, float* __restrict__ as1,
                          float* __restrict__ ad1, int n8){
  int idx = blockIdx.x * 256 + threadIdx.x;
  if (idx >= n8) return;
  int h = idx & 7;
  const float* hp = h1 + (size_t)idx * 8;   // == h1[node*64 + h*8]
  float s = 0.0f, d = 0.0f;
  #pragma unroll
  for (int j = 0; j < 8; j++){
    float v = hp[j];
    s += v * a1s[h * 8 + j];
    d += v * a1d[h * 8 + j];
  }
  as1[idx] = s; ad1[idx] = d;
}

// ---------------- layer-1 aggregation: wave per node ----------------
__global__ void agg1_k(const int* __restrict__ rowp, const int* __restrict__ colv,
                       const float* __restrict__ h1, const float* __restrict__ as1,
                       const float* __restrict__ ad1, const float* __restrict__ b1,
                       float* __restrict__ h2in, int n){
  int node = blockIdx.x * 4 + (threadIdx.x >> 6);
  if (node >= n) return;
  int l = threadIdx.x & 63;
  int h = l >> 3;
  float adn = ad1[node * 8 + h];

  // self loop
  float e = as1[node * 8 + h] + adn;
  e = e > 0.0f ? e : 0.2f * e;
  float w = __expf(e);
  float acc = w * h1[(size_t)node * 64 + l];
  float sw = w;

  int beg = rowp[node], end = rowp[node + 1];
  int i = beg;
  for (; i + 1 < end; i += 2){
    int s0 = colv[i], s1 = colv[i + 1];
    float e0 = as1[s0 * 8 + h] + adn;
    float e1 = as1[s1 * 8 + h] + adn;
    float v0 = h1[(size_t)s0 * 64 + l];
    float v1 = h1[(size_t)s1 * 64 + l];
    e0 = e0 > 0.0f ? e0 : 0.2f * e0;
    e1 = e1 > 0.0f ? e1 : 0.2f * e1;
    float w0 = __expf(e0), w1 = __expf(e1);
    acc += w0 * v0; acc += w1 * v1;
    sw += w0 + w1;
  }
  if (i < end){
    int s0 = colv[i];
    float e0 = as1[s0 * 8 + h] + adn;
    e0 = e0 > 0.0f ? e0 : 0.2f * e0;
    float w0 = __expf(e0);
    acc += w0 * h1[(size_t)s0 * 64 + l];
    sw += w0;
  }
  float o = acc / (sw + 1e-16f) + b1[l];
  h2in[(size_t)node * 64 + l] = o > 0.0f ? o : 0.0f;
}

// ---------------- layer-2 projection + logits ----------------
__global__ void gemm2_k(const float* __restrict__ h2in, const float* __restrict__ W2,
                        const float* __restrict__ a2s, const float* __restrict__ a2d,
                        float* __restrict__ h2, float* __restrict__ vs2,
                        float* __restrict__ vd2, int n){
  __shared__ float w2s[64 * 7];
  __shared__ float a2ss[7], a2ds[7];
  int t = threadIdx.x;
  for (int i = t; i < 448; i += 256) w2s[i] = W2[i];   // FIX: block has 256 threads
  if (t < 7){ a2ss[t] = a2s[t]; a2ds[t] = a2d[t]; }    // FIX: was guarded by t>=448
  __syncthreads();
  int node = blockIdx.x * 256 + t;
  if (node >= n) return;
  float acc[7] = {0,0,0,0,0,0,0};
  const float* hr = h2in + (size_t)node * 64;
  for (int k = 0; k < 64; k++){
    float v = hr[k];
    #pragma unroll
    for (int c = 0; c < 7; c++) acc[c] += v * w2s[k * 7 + c];
  }
  float s = 0.0f, d = 0.0f;
  #pragma unroll
  for (int c = 0; c < 7; c++){
    s += acc[c] * a2ss[c];
    d += acc[c] * a2ds[c];
    h2[(size_t)node * 7 + c] = acc[c];
  }
  vs2[node] = s; vd2[node] = d;
}

// ---------------- layer-2 aggregation + log_softmax ----------------
__global__ void agg2_k(const int* __restrict__ rowp, const int* __restrict__ colv,
                       const float* __restrict__ h2, const float* __restrict__ vs2,
                       const float* __restrict__ vd2, const float* __restrict__ b2,
                       float* __restrict__ out, int n){
  int node = blockIdx.x * 256 + threadIdx.x;
  if (node >= n) return;
  float adn = vd2[node];
  float e = vs2[node] + adn;
  e = e > 0.0f ? e : 0.2f * e;
  float w = __expf(e);
  float acc[7];
  #pragma unroll
  for (int c = 0; c < 7; c++) acc[c] = w * h2[(size_t)node * 7 + c];
  float sw = w;
  int beg = rowp[node], end = rowp[node + 1];
  for (int i = beg; i < end; i++){
    int s = colv[i];
    float ee = vs2[s] + adn;
    ee = ee > 0.0f ? ee : 0.2f * ee;
    float ww = __expf(ee);
    const float* hp = h2 + (size_t)s * 7;
    #pragma unroll
    for (int c = 0; c < 7; c++) acc[c] += ww * hp[c];
    sw += ww;
  }
  float inv = 1.0f / (sw + 1e-16f);
  float o[7];
  float m = -1e30f;
  #pragma unroll
  for (int c = 0; c < 7; c++){
    o[c] = acc[c] * inv + b2[c];
    m = fmaxf(m, o[c]);
  }
  float sum = 0.0f;
  #pragma unroll
  for (int c = 0; c < 7; c++) sum += __expf(o[c] - m);
  float lg = __logf(sum);
  #pragma unroll
  for (int c = 0; c < 7; c++) out[(size_t)node * 7 + c] = o[c] - m - lg;
}

extern "C" void kernel_launch(void* const* d_in, const int* in_sizes, int n_in,
                              void* d_out, int out_size, void* d_ws, size_t ws_size,
                              hipStream_t stream){
  const float* x   = (const float*)d_in[0];
  const int*   ei  = (const int*)d_in[1];
  const float* W1  = (const float*)d_in[2];
  const float* a1s = (const float*)d_in[3];
  const float* a1d = (const float*)d_in[4];
  const float* b1  = (const float*)d_in[5];
  const float* W2  = (const float*)d_in[6];
  const float* a2s = (const float*)d_in[7];
  const float* a2d = (const float*)d_in[8];
  const float* b2  = (const float*)d_in[9];
  int E = in_sizes[1] / 2;
  const int* srcs = ei;
  const int* dsts = ei + E;
  int n = in_sizes[0] / FIN;

  char* ws = (char*)d_ws;
  size_t off = 0;
  auto alloc = [&](size_t bytes)->void*{
    void* p = ws + off; off += (bytes + 255) & ~(size_t)255; return p;
  };
  float* h1   = (float*)alloc((size_t)n * 64 * 4);
  float* h2in = (float*)alloc((size_t)n * 64 * 4);
  float* as1  = (float*)alloc((size_t)n * 8 * 4);
  float* ad1  = (float*)alloc((size_t)n * 8 * 4);
  float* h2   = (float*)alloc((size_t)n * 7 * 4);
  float* vs2  = (float*)alloc((size_t)n * 4);
  float* vd2  = (float*)alloc((size_t)n * 4);
  int* counts = (int*)alloc((size_t)n * 4);
  int* rowp   = (int*)alloc((size_t)(n + 1) * 4);
  int* cursor = (int*)alloc((size_t)n * 4);
  int* colv   = (int*)alloc((size_t)E * 4);
  short* w1p  = (short*)alloc((size_t)KSTEPS * 4 * 64 * 8 * 2);
  (void)ws_size; (void)n_in; (void)out_size;

  hipMemsetAsync(counts, 0, (size_t)n * 4, stream);
  hist_k<<<(E + 255) / 256, 256, 0, stream>>>(dsts, counts, E);
  scan_k<<<1, 1024, 0, stream>>>(counts, rowp, cursor, n, E);
  scatter_k<<<(E + 255) / 256, 256, 0, stream>>>(srcs, dsts, cursor, colv, E);
  w1pack_k<<<KSTEPS * 4, 64, 0, stream>>>(W1, w1p);
  gemm1_k<<<(n + 127) / 128, 256, 0, stream>>>(x, w1p, h1, n);
  alphas1_k<<<(n * 8 + 255) / 256, 256, 0, stream>>>(h1, a1s, a1d, as1, ad1, n * 8);
  agg1_k<<<(n + 3) / 4, 256, 0, stream>>>(rowp, colv, h1, as1, ad1, b1, h2in, n);
  gemm2_k<<<(n + 255) / 256, 256, 0, stream>>>(h2in, W2, a2s, a2d, h2, vs2, vd2, n);
  agg2_k<<<(n + 255) / 256, 256, 0, stream>>>(rowp, colv, h2, vs2, vd2, b2, (float*)d_out, n);
}

// Round 3
// 1028.007 us; speedup vs baseline: 1.1773x; 1.1773x over previous
//
#include <hip/hip_runtime.h>

#define NN 100000
#define FIN 1433
#define KSTEPS 45   // ceil(1433/32)

typedef __attribute__((ext_vector_type(8))) short s16x8;
typedef __attribute__((ext_vector_type(4))) float f32x4;

__device__ __forceinline__ short f2bf(float f){
  unsigned u = __float_as_uint(f);
  unsigned r = (u + 0x7fffu + ((u >> 16) & 1u)) >> 16;
  return (short)r;
}

__device__ __forceinline__ f32x4 mfma16(s16x8 a, s16x8 b, f32x4 c){
  return __builtin_amdgcn_mfma_f32_16x16x32_bf16(a, b, c, 0, 0, 0);
}

// ---------------- CSR build ----------------
__global__ void hist_k(const int* __restrict__ dsts, int* __restrict__ counts, int E){
  int i = blockIdx.x * 256 + threadIdx.x;
  if (i < E) atomicAdd(&counts[dsts[i]], 1);
}

__global__ void scan_k(const int* __restrict__ counts, int* __restrict__ rowp,
                       int* __restrict__ cursor, int n, int E){
  __shared__ int sums[1024];
  int t = threadIdx.x;
  int chunk = (n + 1023) / 1024;
  int beg = t * chunk;
  int end = min(beg + chunk, n);
  int s = 0;
  for (int i = beg; i < end; i++) s += counts[i];
  sums[t] = s;
  __syncthreads();
  for (int off = 1; off < 1024; off <<= 1){
    int v = (t >= off) ? sums[t - off] : 0;
    __syncthreads();
    sums[t] += v;
    __syncthreads();
  }
  int run = (t == 0) ? 0 : sums[t - 1];
  for (int i = beg; i < end; i++){
    int c = counts[i];
    rowp[i] = run;
    cursor[i] = run;
    run += c;
  }
  if (t == 1023) rowp[n] = sums[1023];
}

__global__ void scatter_k(const int* __restrict__ srcs, const int* __restrict__ dsts,
                          int* __restrict__ cursor, int* __restrict__ colv, int E){
  int i = blockIdx.x * 256 + threadIdx.x;
  if (i < E){
    int d = dsts[i];
    int p = atomicAdd(&cursor[d], 1);
    colv[p] = srcs[i];
  }
}

// ---------------- W1 fragment prepack ----------------
// pack[((ks*4+nf)*64 + lane)*8 + j] = bf16( W1[(ks*32 + (lane>>4)*8 + j)][nf*16 + (lane&15)] )
__global__ void w1pack_k(const float* __restrict__ W1, short* __restrict__ pack){
  int ks = blockIdx.x >> 2, nf = blockIdx.x & 3, l = threadIdx.x;
  int col = nf * 16 + (l & 15);
  s16x8 v;
  #pragma unroll
  for (int j = 0; j < 8; j++){
    int k = ks * 32 + ((l >> 4) * 8) + j;
    float f = (k < FIN) ? W1[k * 64 + col] : 0.0f;
    v[j] = f2bf(f);
  }
  *(s16x8*)&pack[((size_t)(ks * 4 + nf) * 64 + l) * 8] = v;
}

// ---------------- GEMM1: h1 = x @ W1  [N,64] ----------------
// Direct global->register fragments. No LDS, no barriers: each x element
// feeds exactly one lane's A-fragment, so staging had zero reuse.
__global__ __launch_bounds__(256) void gemm1_k(const float* __restrict__ x,
                                               const short* __restrict__ w1p,
                                               float* __restrict__ h1, int n){
  int tid = threadIdx.x;
  int wid = tid >> 6, lane = tid & 63;
  int row0 = blockIdx.x * 128;
  int g = lane >> 4;                 // k-chunk group 0..3
  f32x4 acc[2][4] = {};

  // clamped rows: out-of-range rows read row n-1 (garbage only lands in
  // unstored D rows)
  int r0 = min(row0 + wid * 32 +      (lane & 15), n - 1);
  int r1 = min(row0 + wid * 32 + 16 + (lane & 15), n - 1);
  const float* pa0 = x + (size_t)r0 * FIN + g * 8;
  const float* pa1 = x + (size_t)r1 * FIN + g * 8;
  const s16x8* pb  = ((const s16x8*)w1p) + lane;

  #pragma unroll 2
  for (int ks = 0; ks < 44; ks++){   // k0 = ks*32, covers k < 1408
    float av0[8], av1[8];
    #pragma unroll
    for (int j = 0; j < 8; j++){
      av0[j] = pa0[ks * 32 + j];
      av1[j] = pa1[ks * 32 + j];
    }
    s16x8 b0 = pb[(ks * 4 + 0) * 64];
    s16x8 b1 = pb[(ks * 4 + 1) * 64];
    s16x8 b2 = pb[(ks * 4 + 2) * 64];
    s16x8 b3 = pb[(ks * 4 + 3) * 64];
    s16x8 a0, a1;
    #pragma unroll
    for (int j = 0; j < 8; j++){ a0[j] = f2bf(av0[j]); a1[j] = f2bf(av1[j]); }
    acc[0][0] = mfma16(a0, b0, acc[0][0]);
    acc[0][1] = mfma16(a0, b1, acc[0][1]);
    acc[0][2] = mfma16(a0, b2, acc[0][2]);
    acc[0][3] = mfma16(a0, b3, acc[0][3]);
    acc[1][0] = mfma16(a1, b0, acc[1][0]);
    acc[1][1] = mfma16(a1, b1, acc[1][1]);
    acc[1][2] = mfma16(a1, b2, acc[1][2]);
    acc[1][3] = mfma16(a1, b3, acc[1][3]);
  }
  { // tail: k0 = 1408, guard k < 1433  <=>  g*8+j < 25
    const int ks = 44;
    float av0[8], av1[8];
    #pragma unroll
    for (int j = 0; j < 8; j++){
      bool ok = (g * 8 + j) < 25;
      av0[j] = ok ? pa0[ks * 32 + j] : 0.0f;
      av1[j] = ok ? pa1[ks * 32 + j] : 0.0f;
    }
    s16x8 b0 = pb[(ks * 4 + 0) * 64];
    s16x8 b1 = pb[(ks * 4 + 1) * 64];
    s16x8 b2 = pb[(ks * 4 + 2) * 64];
    s16x8 b3 = pb[(ks * 4 + 3) * 64];
    s16x8 a0, a1;
    #pragma unroll
    for (int j = 0; j < 8; j++){ a0[j] = f2bf(av0[j]); a1[j] = f2bf(av1[j]); }
    acc[0][0] = mfma16(a0, b0, acc[0][0]);
    acc[0][1] = mfma16(a0, b1, acc[0][1]);
    acc[0][2] = mfma16(a0, b2, acc[0][2]);
    acc[0][3] = mfma16(a0, b3, acc[0][3]);
    acc[1][0] = mfma16(a1, b0, acc[1][0]);
    acc[1][1] = mfma16(a1, b1, acc[1][1]);
    acc[1][2] = mfma16(a1, b2, acc[1][2]);
    acc[1][3] = mfma16(a1, b3, acc[1][3]);
  }

  // epilogue: D lane l reg r -> (m=(l>>4)*4+r, ncol=l&15)
  #pragma unroll
  for (int mf = 0; mf < 2; mf++){
    #pragma unroll
    for (int r4 = 0; r4 < 4; r4++){
      int m = row0 + wid * 32 + mf * 16 + (lane >> 4) * 4 + r4;
      if (m < n){
        #pragma unroll
        for (int nf = 0; nf < 4; nf++)
          h1[(size_t)m * 64 + nf * 16 + (lane & 15)] = acc[mf][nf][r4];
      }
    }
  }
}

// ---------------- per-node attention logits, layer 1 ----------------
__global__ void alphas1_k(const float* __restrict__ h1, const float* __restrict__ a1s,
                          const float* __restrict__ a1d, float* __restrict__ as1,
                          float* __restrict__ ad1, int n8){
  int idx = blockIdx.x * 256 + threadIdx.x;
  if (idx >= n8) return;
  int h = idx & 7;
  const float* hp = h1 + (size_t)idx * 8;   // == h1[node*64 + h*8]
  float s = 0.0f, d = 0.0f;
  #pragma unroll
  for (int j = 0; j < 8; j++){
    float v = hp[j];
    s += v * a1s[h * 8 + j];
    d += v * a1d[h * 8 + j];
  }
  as1[idx] = s; ad1[idx] = d;
}

// ---------------- layer-1 aggregation: wave per node ----------------
__global__ void agg1_k(const int* __restrict__ rowp, const int* __restrict__ colv,
                       const float* __restrict__ h1, const float* __restrict__ as1,
                       const float* __restrict__ ad1, const float* __restrict__ b1,
                       float* __restrict__ h2in, int n){
  int node = blockIdx.x * 4 + (threadIdx.x >> 6);
  if (node >= n) return;
  int l = threadIdx.x & 63;
  int h = l >> 3;
  float adn = ad1[node * 8 + h];

  // self loop
  float e = as1[node * 8 + h] + adn;
  e = e > 0.0f ? e : 0.2f * e;
  float w = __expf(e);
  float acc = w * h1[(size_t)node * 64 + l];
  float sw = w;

  int beg = rowp[node], end = rowp[node + 1];
  int i = beg;
  for (; i + 3 < end; i += 4){
    int s0 = colv[i], s1 = colv[i + 1], s2 = colv[i + 2], s3 = colv[i + 3];
    float e0 = as1[s0 * 8 + h] + adn;
    float e1 = as1[s1 * 8 + h] + adn;
    float e2 = as1[s2 * 8 + h] + adn;
    float e3 = as1[s3 * 8 + h] + adn;
    float v0 = h1[(size_t)s0 * 64 + l];
    float v1 = h1[(size_t)s1 * 64 + l];
    float v2 = h1[(size_t)s2 * 64 + l];
    float v3 = h1[(size_t)s3 * 64 + l];
    e0 = e0 > 0.0f ? e0 : 0.2f * e0;
    e1 = e1 > 0.0f ? e1 : 0.2f * e1;
    e2 = e2 > 0.0f ? e2 : 0.2f * e2;
    e3 = e3 > 0.0f ? e3 : 0.2f * e3;
    float w0 = __expf(e0), w1 = __expf(e1), w2 = __expf(e2), w3 = __expf(e3);
    acc += w0 * v0 + w1 * v1 + w2 * v2 + w3 * v3;
    sw  += w0 + w1 + w2 + w3;
  }
  for (; i < end; i++){
    int s0 = colv[i];
    float e0 = as1[s0 * 8 + h] + adn;
    e0 = e0 > 0.0f ? e0 : 0.2f * e0;
    float w0 = __expf(e0);
    acc += w0 * h1[(size_t)s0 * 64 + l];
    sw += w0;
  }
  float o = acc / (sw + 1e-16f) + b1[l];
  h2in[(size_t)node * 64 + l] = o > 0.0f ? o : 0.0f;
}

// ---------------- layer-2 projection + logits ----------------
__global__ void gemm2_k(const float* __restrict__ h2in, const float* __restrict__ W2,
                        const float* __restrict__ a2s, const float* __restrict__ a2d,
                        float* __restrict__ h2, float* __restrict__ vs2,
                        float* __restrict__ vd2, int n){
  __shared__ float w2s[64 * 7];
  __shared__ float a2ss[7], a2ds[7];
  int t = threadIdx.x;
  for (int i = t; i < 448; i += 256) w2s[i] = W2[i];
  if (t < 7){ a2ss[t] = a2s[t]; a2ds[t] = a2d[t]; }
  __syncthreads();
  int node = blockIdx.x * 256 + t;
  if (node >= n) return;
  float acc[7] = {0,0,0,0,0,0,0};
  const float* hr = h2in + (size_t)node * 64;
  for (int k = 0; k < 64; k++){
    float v = hr[k];
    #pragma unroll
    for (int c = 0; c < 7; c++) acc[c] += v * w2s[k * 7 + c];
  }
  float s = 0.0f, d = 0.0f;
  #pragma unroll
  for (int c = 0; c < 7; c++){
    s += acc[c] * a2ss[c];
    d += acc[c] * a2ds[c];
    h2[(size_t)node * 7 + c] = acc[c];
  }
  vs2[node] = s; vd2[node] = d;
}

// ---------------- layer-2 aggregation + log_softmax ----------------
// 8 lanes per node: lane c<7 owns class c. 8x the memory-level parallelism
// of the old per-thread serial version.
__global__ void agg2_k(const int* __restrict__ rowp, const int* __restrict__ colv,
                       const float* __restrict__ h2, const float* __restrict__ vs2,
                       const float* __restrict__ vd2, const float* __restrict__ b2,
                       float* __restrict__ out, int n){
  int t = threadIdx.x;
  int node = blockIdx.x * 32 + (t >> 3);
  int c = t & 7;
  if (node >= n) return;
  bool cls = c < 7;
  float adn = vd2[node];
  float e = vs2[node] + adn;
  e = e > 0.0f ? e : 0.2f * e;
  float w = __expf(e);
  float acc = cls ? w * h2[(size_t)node * 7 + c] : 0.0f;
  float sw = w;
  int beg = rowp[node], end = rowp[node + 1];
  int i = beg;
  for (; i + 1 < end; i += 2){
    int s0 = colv[i], s1 = colv[i + 1];
    float e0 = vs2[s0] + adn;
    float e1 = vs2[s1] + adn;
    float v0 = cls ? h2[(size_t)s0 * 7 + c] : 0.0f;
    float v1 = cls ? h2[(size_t)s1 * 7 + c] : 0.0f;
    e0 = e0 > 0.0f ? e0 : 0.2f * e0;
    e1 = e1 > 0.0f ? e1 : 0.2f * e1;
    float w0 = __expf(e0), w1 = __expf(e1);
    acc += w0 * v0 + w1 * v1;
    sw += w0 + w1;
  }
  for (; i < end; i++){
    int s0 = colv[i];
    float e0 = vs2[s0] + adn;
    e0 = e0 > 0.0f ? e0 : 0.2f * e0;
    float w0 = __expf(e0);
    acc += w0 * (cls ? h2[(size_t)s0 * 7 + c] : 0.0f);
    sw += w0;
  }
  float inv = 1.0f / (sw + 1e-16f);
  float o = cls ? acc * inv + b2[c] : -1e30f;
  // log-softmax across the 8-lane group (lane 7 is padding)
  float m = o;
  m = fmaxf(m, __shfl_xor(m, 1, 8));
  m = fmaxf(m, __shfl_xor(m, 2, 8));
  m = fmaxf(m, __shfl_xor(m, 4, 8));
  float ex = cls ? __expf(o - m) : 0.0f;
  float s8 = ex;
  s8 += __shfl_xor(s8, 1, 8);
  s8 += __shfl_xor(s8, 2, 8);
  s8 += __shfl_xor(s8, 4, 8);
  if (cls) out[(size_t)node * 7 + c] = o - m - __logf(s8);
}

extern "C" void kernel_launch(void* const* d_in, const int* in_sizes, int n_in,
                              void* d_out, int out_size, void* d_ws, size_t ws_size,
                              hipStream_t stream){
  const float* x   = (const float*)d_in[0];
  const int*   ei  = (const int*)d_in[1];
  const float* W1  = (const float*)d_in[2];
  const float* a1s = (const float*)d_in[3];
  const float* a1d = (const float*)d_in[4];
  const float* b1  = (const float*)d_in[5];
  const float* W2  = (const float*)d_in[6];
  const float* a2s = (const float*)d_in[7];
  const float* a2d = (const float*)d_in[8];
  const float* b2  = (const float*)d_in[9];
  int E = in_sizes[1] / 2;
  const int* srcs = ei;
  const int* dsts = ei + E;
  int n = in_sizes[0] / FIN;

  char* ws = (char*)d_ws;
  size_t off = 0;
  auto alloc = [&](size_t bytes)->void*{
    void* p = ws + off; off += (bytes + 255) & ~(size_t)255; return p;
  };
  float* h1   = (float*)alloc((size_t)n * 64 * 4);
  float* h2in = (float*)alloc((size_t)n * 64 * 4);
  float* as1  = (float*)alloc((size_t)n * 8 * 4);
  float* ad1  = (float*)alloc((size_t)n * 8 * 4);
  float* h2   = (float*)alloc((size_t)n * 7 * 4);
  float* vs2  = (float*)alloc((size_t)n * 4);
  float* vd2  = (float*)alloc((size_t)n * 4);
  int* counts = (int*)alloc((size_t)n * 4);
  int* rowp   = (int*)alloc((size_t)(n + 1) * 4);
  int* cursor = (int*)alloc((size_t)n * 4);
  int* colv   = (int*)alloc((size_t)E * 4);
  short* w1p  = (short*)alloc((size_t)KSTEPS * 4 * 64 * 8 * 2);
  (void)ws_size; (void)n_in; (void)out_size;

  hipMemsetAsync(counts, 0, (size_t)n * 4, stream);
  hist_k<<<(E + 255) / 256, 256, 0, stream>>>(dsts, counts, E);
  scan_k<<<1, 1024, 0, stream>>>(counts, rowp, cursor, n, E);
  scatter_k<<<(E + 255) / 256, 256, 0, stream>>>(srcs, dsts, cursor, colv, E);
  w1pack_k<<<KSTEPS * 4, 64, 0, stream>>>(W1, w1p);
  gemm1_k<<<(n + 127) / 128, 256, 0, stream>>>(x, w1p, h1, n);
  alphas1_k<<<(n * 8 + 255) / 256, 256, 0, stream>>>(h1, a1s, a1d, as1, ad1, n * 8);
  agg1_k<<<(n + 3) / 4, 256, 0, stream>>>(rowp, colv, h1, as1, ad1, b1, h2in, n);
  gemm2_k<<<(n + 255) / 256, 256, 0, stream>>>(h2in, W2, a2s, a2d, h2, vs2, vd2, n);
  agg2_k<<<(n + 31) / 32, 256, 0, stream>>>(rowp, colv, h2, vs2, vd2, b2, (float*)d_out, n);
}

// Round 4
// 887.217 us; speedup vs baseline: 1.3641x; 1.1587x over previous
//
#include <hip/hip_runtime.h>

#define NN 100000
#define FIN 1433
#define KSTEPS 45        // ceil(1433/32)
#define NPAD 100352      // 98 * 1024 (scan padding)
#define PSB 98           // scan phase-1 blocks

typedef __attribute__((ext_vector_type(8))) short s16x8;
typedef __attribute__((ext_vector_type(4))) float f32x4;

__device__ __forceinline__ short f2bf(float f){
  unsigned u = __float_as_uint(f);
  unsigned r = (u + 0x7fffu + ((u >> 16) & 1u)) >> 16;
  return (short)r;
}
__device__ __forceinline__ float bflo(unsigned u){ return __uint_as_float(u << 16); }
__device__ __forceinline__ float bfhi(unsigned u){ return __uint_as_float(u & 0xffff0000u); }

__device__ __forceinline__ f32x4 mfma16(s16x8 a, s16x8 b, f32x4 c){
  return __builtin_amdgcn_mfma_f32_16x16x32_bf16(a, b, c, 0, 0, 0);
}

// ---------------- CSR build ----------------
__global__ void init_k(int* __restrict__ counts, int n){
  int i = blockIdx.x * 256 + threadIdx.x;
  if (i < NPAD) counts[i] = (i < n) ? 1 : 0;   // 1 = reserved self-loop slot
}

__global__ void hist_k(const int* __restrict__ dsts, int* __restrict__ counts, int E){
  int i = blockIdx.x * 256 + threadIdx.x;
  if (i < E) atomicAdd(&counts[dsts[i]], 1);
}

// phase 1: per-block (1024 elems) int4 prefix + block sums
__global__ void psum_k(const int* __restrict__ counts, int* __restrict__ pre,
                       int* __restrict__ bsum){
  __shared__ int ls[256];
  int blk = blockIdx.x, t = threadIdx.x;
  int4 v = ((const int4*)(counts + blk * 1024))[t];
  int s = v.x + v.y + v.z + v.w;
  ls[t] = s;
  __syncthreads();
  for (int off = 1; off < 256; off <<= 1){
    int u = (t >= off) ? ls[t - off] : 0;
    __syncthreads();
    ls[t] += u;
    __syncthreads();
  }
  int excl = ls[t] - s;
  int4 o;
  o.x = excl; o.y = o.x + v.x; o.z = o.y + v.y; o.w = o.z + v.z;
  ((int4*)(pre + blk * 1024))[t] = o;
  if (t == 255) bsum[blk] = ls[255];
}

// phase 2: scan the 98 block sums
__global__ void scan2_k(const int* __restrict__ bsum, int* __restrict__ boff){
  __shared__ int ls[128];
  int t = threadIdx.x;
  int v = (t < PSB) ? bsum[t] : 0;
  ls[t] = v;
  __syncthreads();
  for (int off = 1; off < 128; off <<= 1){
    int u = (t >= off) ? ls[t - off] : 0;
    __syncthreads();
    ls[t] += u;
    __syncthreads();
  }
  if (t < PSB) boff[t] = ls[t] - v;
}

// phase 3: add block offsets -> rowp, cursor
__global__ void addoff_k(const int* __restrict__ pre, const int* __restrict__ boff,
                         int* __restrict__ rowp, int* __restrict__ cursor){
  int blk = blockIdx.x, t = threadIdx.x;
  int off = boff[blk];
  int4 p = ((const int4*)(pre + blk * 1024))[t];
  p.x += off; p.y += off; p.z += off; p.w += off;
  ((int4*)(rowp + blk * 1024))[t] = p;
  ((int4*)(cursor + blk * 1024))[t] = p;
}

__global__ void selfloop_k(const int* __restrict__ rowp, int* __restrict__ cursor,
                           int* __restrict__ colv, int n){
  int i = blockIdx.x * 256 + threadIdx.x;
  if (i < n){
    int p = rowp[i];
    colv[p] = i;
    cursor[i] = p + 1;
  }
}

__global__ void scatter_k(const int* __restrict__ srcs, const int* __restrict__ dsts,
                          int* __restrict__ cursor, int* __restrict__ colv, int E){
  int i = blockIdx.x * 256 + threadIdx.x;
  if (i < E){
    int d = dsts[i];
    int p = atomicAdd(&cursor[d], 1);
    colv[p] = srcs[i];
  }
}

// ---------------- W1 fragment prepack ----------------
__global__ void w1pack_k(const float* __restrict__ W1, short* __restrict__ pack){
  int ks = blockIdx.x >> 2, nf = blockIdx.x & 3, l = threadIdx.x;
  int col = nf * 16 + (l & 15);
  s16x8 v;
  #pragma unroll
  for (int j = 0; j < 8; j++){
    int k = ks * 32 + ((l >> 4) * 8) + j;
    float f = (k < FIN) ? W1[k * 64 + col] : 0.0f;
    v[j] = f2bf(f);
  }
  *(s16x8*)&pack[((size_t)(ks * 4 + nf) * 64 + l) * 8] = v;
}

// ---------------- GEMM1: h1b = bf16(x @ W1)  [N,64] ----------------
// Direct global->register A fragments, explicit next-iter register prefetch.
__global__ __launch_bounds__(256) void gemm1_k(const float* __restrict__ x,
                                               const short* __restrict__ w1p,
                                               unsigned short* __restrict__ h1b, int n){
  int tid = threadIdx.x;
  int wid = tid >> 6, lane = tid & 63;
  int row0 = blockIdx.x * 128;
  int g = lane >> 4;
  f32x4 acc[2][4] = {};

  int r0 = min(row0 + wid * 32 +      (lane & 15), n - 1);
  int r1 = min(row0 + wid * 32 + 16 + (lane & 15), n - 1);
  const float* pa0 = x + (size_t)r0 * FIN + g * 8;
  const float* pa1 = x + (size_t)r1 * FIN + g * 8;
  const s16x8* pb  = ((const s16x8*)w1p) + lane;

  float c0[8], c1[8], n0[8], n1[8];
  #pragma unroll
  for (int j = 0; j < 8; j++){
    c0[j] = __builtin_nontemporal_load(pa0 + j);
    c1[j] = __builtin_nontemporal_load(pa1 + j);
  }

  #pragma unroll 2
  for (int ks = 0; ks < 43; ks++){
    const float* q0 = pa0 + (ks + 1) * 32;
    const float* q1 = pa1 + (ks + 1) * 32;
    #pragma unroll
    for (int j = 0; j < 8; j++){
      n0[j] = __builtin_nontemporal_load(q0 + j);
      n1[j] = __builtin_nontemporal_load(q1 + j);
    }
    s16x8 b0 = pb[(ks * 4 + 0) * 64];
    s16x8 b1 = pb[(ks * 4 + 1) * 64];
    s16x8 b2 = pb[(ks * 4 + 2) * 64];
    s16x8 b3 = pb[(ks * 4 + 3) * 64];
    s16x8 a0, a1;
    #pragma unroll
    for (int j = 0; j < 8; j++){ a0[j] = f2bf(c0[j]); a1[j] = f2bf(c1[j]); }
    acc[0][0] = mfma16(a0, b0, acc[0][0]);
    acc[0][1] = mfma16(a0, b1, acc[0][1]);
    acc[0][2] = mfma16(a0, b2, acc[0][2]);
    acc[0][3] = mfma16(a0, b3, acc[0][3]);
    acc[1][0] = mfma16(a1, b0, acc[1][0]);
    acc[1][1] = mfma16(a1, b1, acc[1][1]);
    acc[1][2] = mfma16(a1, b2, acc[1][2]);
    acc[1][3] = mfma16(a1, b3, acc[1][3]);
    #pragma unroll
    for (int j = 0; j < 8; j++){ c0[j] = n0[j]; c1[j] = n1[j]; }
  }

  { // ks=43: prefetch masked tail (k0=1408, valid k offsets: g*8+j < 25)
    const float* q0 = pa0 + 44 * 32;
    const float* q1 = pa1 + 44 * 32;
    #pragma unroll
    for (int j = 0; j < 8; j++){
      bool ok = (g * 8 + j) < 25;
      int jj = ok ? j : 0;               // j=0 always in-bounds for all g
      float v0 = __builtin_nontemporal_load(q0 + jj);
      float v1 = __builtin_nontemporal_load(q1 + jj);
      n0[j] = ok ? v0 : 0.0f;
      n1[j] = ok ? v1 : 0.0f;
    }
    const int ks = 43;
    s16x8 b0 = pb[(ks * 4 + 0) * 64];
    s16x8 b1 = pb[(ks * 4 + 1) * 64];
    s16x8 b2 = pb[(ks * 4 + 2) * 64];
    s16x8 b3 = pb[(ks * 4 + 3) * 64];
    s16x8 a0, a1;
    #pragma unroll
    for (int j = 0; j < 8; j++){ a0[j] = f2bf(c0[j]); a1[j] = f2bf(c1[j]); }
    acc[0][0] = mfma16(a0, b0, acc[0][0]);
    acc[0][1] = mfma16(a0, b1, acc[0][1]);
    acc[0][2] = mfma16(a0, b2, acc[0][2]);
    acc[0][3] = mfma16(a0, b3, acc[0][3]);
    acc[1][0] = mfma16(a1, b0, acc[1][0]);
    acc[1][1] = mfma16(a1, b1, acc[1][1]);
    acc[1][2] = mfma16(a1, b2, acc[1][2]);
    acc[1][3] = mfma16(a1, b3, acc[1][3]);
    #pragma unroll
    for (int j = 0; j < 8; j++){ c0[j] = n0[j]; c1[j] = n1[j]; }
  }
  { // ks=44 tail compute
    const int ks = 44;
    s16x8 b0 = pb[(ks * 4 + 0) * 64];
    s16x8 b1 = pb[(ks * 4 + 1) * 64];
    s16x8 b2 = pb[(ks * 4 + 2) * 64];
    s16x8 b3 = pb[(ks * 4 + 3) * 64];
    s16x8 a0, a1;
    #pragma unroll
    for (int j = 0; j < 8; j++){ a0[j] = f2bf(c0[j]); a1[j] = f2bf(c1[j]); }
    acc[0][0] = mfma16(a0, b0, acc[0][0]);
    acc[0][1] = mfma16(a0, b1, acc[0][1]);
    acc[0][2] = mfma16(a0, b2, acc[0][2]);
    acc[0][3] = mfma16(a0, b3, acc[0][3]);
    acc[1][0] = mfma16(a1, b0, acc[1][0]);
    acc[1][1] = mfma16(a1, b1, acc[1][1]);
    acc[1][2] = mfma16(a1, b2, acc[1][2]);
    acc[1][3] = mfma16(a1, b3, acc[1][3]);
  }

  // epilogue: pack pairs (cols l15, l15^1) to bf16 dwords; even lanes store.
  // m depends only on lane>>4, so the m<n predicate is pair-uniform (safe shfl).
  #pragma unroll
  for (int mf = 0; mf < 2; mf++){
    #pragma unroll
    for (int r4 = 0; r4 < 4; r4++){
      int m = row0 + wid * 32 + mf * 16 + (lane >> 4) * 4 + r4;
      if (m < n){
        #pragma unroll
        for (int nf = 0; nf < 4; nf++){
          float v = acc[mf][nf][r4];
          float pv = __shfl_xor(v, 1);
          if ((lane & 1) == 0){
            unsigned pk = (unsigned)(unsigned short)f2bf(v) |
                          ((unsigned)(unsigned short)f2bf(pv) << 16);
            *(unsigned*)&h1b[(size_t)m * 64 + nf * 16 + (lane & 15)] = pk;
          }
        }
      }
    }
  }
}

// ---------------- per-(node,head) attention logits, layer 1 ----------------
__global__ void alphas1_k(const unsigned short* __restrict__ h1b,
                          const float* __restrict__ a1s, const float* __restrict__ a1d,
                          float* __restrict__ as1, float* __restrict__ ad1, int n8){
  int idx = blockIdx.x * 256 + threadIdx.x;
  if (idx >= n8) return;
  int h = idx & 7;
  uint4 u = ((const uint4*)h1b)[idx];   // 8 bf16 = 16B
  float f[8] = { bflo(u.x), bfhi(u.x), bflo(u.y), bfhi(u.y),
                 bflo(u.z), bfhi(u.z), bflo(u.w), bfhi(u.w) };
  float s = 0.0f, d = 0.0f;
  #pragma unroll
  for (int j = 0; j < 8; j++){
    s += f[j] * a1s[h * 8 + j];
    d += f[j] * a1d[h * 8 + j];
  }
  as1[idx] = s; ad1[idx] = d;
}

// ---------------- layer-1 aggregation: wave per node, 2 edges in parallel ----
// lanes 0..31 = half-wave 0, lanes 32..63 = half-wave 1; lane sl owns features
// (2sl, 2sl+1) via one dword bf16x2 read. Self-loop is in the CSR.
__global__ void agg1_k(const int* __restrict__ rowp, const int* __restrict__ colv,
                       const unsigned short* __restrict__ h1b,
                       const float* __restrict__ as1, const float* __restrict__ ad1,
                       const float* __restrict__ b1, float* __restrict__ h2in, int n){
  int node = blockIdx.x * 4 + (threadIdx.x >> 6);
  if (node >= n) return;
  int l = threadIdx.x & 63, sl = l & 31, hw = l >> 5;
  int h = sl >> 2;                       // head of features 2sl,2sl+1
  float adn = ad1[node * 8 + h];
  float accx = 0.0f, accy = 0.0f, sw = 0.0f;
  int beg = rowp[node], end = rowp[node + 1];

  int i = beg + hw;
  for (; i + 2 < end; i += 4){
    int s0 = colv[i], s1 = colv[i + 2];
    float e0 = as1[s0 * 8 + h] + adn;
    float e1 = as1[s1 * 8 + h] + adn;
    unsigned u0 = *(const unsigned*)(h1b + (size_t)s0 * 64 + 2 * sl);
    unsigned u1 = *(const unsigned*)(h1b + (size_t)s1 * 64 + 2 * sl);
    e0 = e0 > 0.0f ? e0 : 0.2f * e0;
    e1 = e1 > 0.0f ? e1 : 0.2f * e1;
    float w0 = __expf(e0), w1 = __expf(e1);
    accx += w0 * bflo(u0) + w1 * bflo(u1);
    accy += w0 * bfhi(u0) + w1 * bfhi(u1);
    sw += w0 + w1;
  }
  if (i < end){
    int s0 = colv[i];
    float e0 = as1[s0 * 8 + h] + adn;
    unsigned u0 = *(const unsigned*)(h1b + (size_t)s0 * 64 + 2 * sl);
    e0 = e0 > 0.0f ? e0 : 0.2f * e0;
    float w0 = __expf(e0);
    accx += w0 * bflo(u0);
    accy += w0 * bfhi(u0);
    sw += w0;
  }

  sw   += __shfl_xor(sw, 32);
  accx += __shfl_xor(accx, 32);
  accy += __shfl_xor(accy, 32);
  if (hw == 0){
    float inv = 1.0f / (sw + 1e-16f);
    float bx = b1[2 * sl], by = b1[2 * sl + 1];
    float ox = accx * inv + bx;
    float oy = accy * inv + by;
    float2 o = make_float2(ox > 0.0f ? ox : 0.0f, oy > 0.0f ? oy : 0.0f);
    *(float2*)&h2in[(size_t)node * 64 + 2 * sl] = o;
  }
}

// ---------------- layer-2 projection + logits ----------------
__global__ void gemm2_k(const float* __restrict__ h2in, const float* __restrict__ W2,
                        const float* __restrict__ a2s, const float* __restrict__ a2d,
                        float* __restrict__ h2, float* __restrict__ vs2,
                        float* __restrict__ vd2, int n){
  __shared__ float w2s[64 * 7];
  __shared__ float a2ss[7], a2ds[7];
  int t = threadIdx.x;
  for (int i = t; i < 448; i += 256) w2s[i] = W2[i];
  if (t < 7){ a2ss[t] = a2s[t]; a2ds[t] = a2d[t]; }
  __syncthreads();
  int node = blockIdx.x * 256 + t;
  if (node >= n) return;
  float acc[7] = {0,0,0,0,0,0,0};
  const float4* hr4 = (const float4*)(h2in + (size_t)node * 64);
  #pragma unroll
  for (int k4 = 0; k4 < 16; k4++){
    float4 v = hr4[k4];
    #pragma unroll
    for (int c = 0; c < 7; c++){
      acc[c] += v.x * w2s[(4 * k4 + 0) * 7 + c];
      acc[c] += v.y * w2s[(4 * k4 + 1) * 7 + c];
      acc[c] += v.z * w2s[(4 * k4 + 2) * 7 + c];
      acc[c] += v.w * w2s[(4 * k4 + 3) * 7 + c];
    }
  }
  float s = 0.0f, d = 0.0f;
  #pragma unroll
  for (int c = 0; c < 7; c++){
    s += acc[c] * a2ss[c];
    d += acc[c] * a2ds[c];
    h2[(size_t)node * 7 + c] = acc[c];
  }
  vs2[node] = s; vd2[node] = d;
}

// ---------------- layer-2 aggregation + log_softmax (8 lanes/node) ----------
__global__ void agg2_k(const int* __restrict__ rowp, const int* __restrict__ colv,
                       const float* __restrict__ h2, const float* __restrict__ vs2,
                       const float* __restrict__ vd2, const float* __restrict__ b2,
                       float* __restrict__ out, int n){
  int t = threadIdx.x;
  int node = blockIdx.x * 32 + (t >> 3);
  int c = t & 7;
  if (node >= n) return;
  bool cls = c < 7;
  float adn = vd2[node];
  float acc = 0.0f, sw = 0.0f;
  int beg = rowp[node], end = rowp[node + 1];   // includes self-loop
  int i = beg;
  for (; i + 1 < end; i += 2){
    int s0 = colv[i], s1 = colv[i + 1];
    float e0 = vs2[s0] + adn;
    float e1 = vs2[s1] + adn;
    float v0 = cls ? h2[(size_t)s0 * 7 + c] : 0.0f;
    float v1 = cls ? h2[(size_t)s1 * 7 + c] : 0.0f;
    e0 = e0 > 0.0f ? e0 : 0.2f * e0;
    e1 = e1 > 0.0f ? e1 : 0.2f * e1;
    float w0 = __expf(e0), w1 = __expf(e1);
    acc += w0 * v0 + w1 * v1;
    sw += w0 + w1;
  }
  for (; i < end; i++){
    int s0 = colv[i];
    float e0 = vs2[s0] + adn;
    e0 = e0 > 0.0f ? e0 : 0.2f * e0;
    float w0 = __expf(e0);
    acc += w0 * (cls ? h2[(size_t)s0 * 7 + c] : 0.0f);
    sw += w0;
  }
  float inv = 1.0f / (sw + 1e-16f);
  float o = cls ? acc * inv + b2[c] : -1e30f;
  float m = o;
  m = fmaxf(m, __shfl_xor(m, 1, 8));
  m = fmaxf(m, __shfl_xor(m, 2, 8));
  m = fmaxf(m, __shfl_xor(m, 4, 8));
  float ex = cls ? __expf(o - m) : 0.0f;
  float s8 = ex;
  s8 += __shfl_xor(s8, 1, 8);
  s8 += __shfl_xor(s8, 2, 8);
  s8 += __shfl_xor(s8, 4, 8);
  if (cls) out[(size_t)node * 7 + c] = o - m - __logf(s8);
}

extern "C" void kernel_launch(void* const* d_in, const int* in_sizes, int n_in,
                              void* d_out, int out_size, void* d_ws, size_t ws_size,
                              hipStream_t stream){
  const float* x   = (const float*)d_in[0];
  const int*   ei  = (const int*)d_in[1];
  const float* W1  = (const float*)d_in[2];
  const float* a1s = (const float*)d_in[3];
  const float* a1d = (const float*)d_in[4];
  const float* b1  = (const float*)d_in[5];
  const float* W2  = (const float*)d_in[6];
  const float* a2s = (const float*)d_in[7];
  const float* a2d = (const float*)d_in[8];
  const float* b2  = (const float*)d_in[9];
  int E = in_sizes[1] / 2;
  const int* srcs = ei;
  const int* dsts = ei + E;
  int n = in_sizes[0] / FIN;

  char* ws = (char*)d_ws;
  size_t off = 0;
  auto alloc = [&](size_t bytes)->void*{
    void* p = ws + off; off += (bytes + 255) & ~(size_t)255; return p;
  };
  unsigned short* h1b = (unsigned short*)alloc((size_t)n * 64 * 2);
  float* h2in = (float*)alloc((size_t)n * 64 * 4);
  float* as1  = (float*)alloc((size_t)n * 8 * 4);
  float* ad1  = (float*)alloc((size_t)n * 8 * 4);
  float* h2   = (float*)alloc((size_t)n * 7 * 4);
  float* vs2  = (float*)alloc((size_t)n * 4);
  float* vd2  = (float*)alloc((size_t)n * 4);
  int* counts = (int*)alloc((size_t)NPAD * 4);
  int* pre    = (int*)alloc((size_t)NPAD * 4);
  int* rowp   = (int*)alloc((size_t)NPAD * 4);   // covers n+1
  int* cursor = (int*)alloc((size_t)NPAD * 4);
  int* bsum   = (int*)alloc((size_t)PSB * 4);
  int* boff   = (int*)alloc((size_t)PSB * 4);
  int* colv   = (int*)alloc((size_t)(E + n) * 4);
  short* w1p  = (short*)alloc((size_t)KSTEPS * 4 * 64 * 8 * 2);
  (void)ws_size; (void)n_in; (void)out_size;

  init_k<<<(NPAD + 255) / 256, 256, 0, stream>>>(counts, n);
  hist_k<<<(E + 255) / 256, 256, 0, stream>>>(dsts, counts, E);
  psum_k<<<PSB, 256, 0, stream>>>(counts, pre, bsum);
  scan2_k<<<1, 128, 0, stream>>>(bsum, boff);
  addoff_k<<<PSB, 256, 0, stream>>>(pre, boff, rowp, cursor);
  selfloop_k<<<(n + 255) / 256, 256, 0, stream>>>(rowp, cursor, colv, n);
  scatter_k<<<(E + 255) / 256, 256, 0, stream>>>(srcs, dsts, cursor, colv, E);
  w1pack_k<<<KSTEPS * 4, 64, 0, stream>>>(W1, w1p);
  gemm1_k<<<(n + 127) / 128, 256, 0, stream>>>(x, w1p, h1b, n);
  alphas1_k<<<(n * 8 + 255) / 256, 256, 0, stream>>>(h1b, a1s, a1d, as1, ad1, n * 8);
  agg1_k<<<(n + 3) / 4, 256, 0, stream>>>(rowp, colv, h1b, as1, ad1, b1, h2in, n);
  gemm2_k<<<(n + 255) / 256, 256, 0, stream>>>(h2in, W2, a2s, a2d, h2, vs2, vd2, n);
  agg2_k<<<(n + 31) / 32, 256, 0, stream>>>(rowp, colv, h2, vs2, vd2, b2, (float*)d_out, n);
}